// Round 1
// baseline (678.358 us; speedup 1.0000x reference)
//
#include <hip/hip_runtime.h>

#define BB 512
#define LL 1024
#define TT 52
#define START_TAG 50   // T-2
#define STOP_TAG  51   // T-1

// broadcast p from lane i (wave-uniform result lands in an SGPR)
__device__ __forceinline__ float rl(float v, int i) {
  return __uint_as_float(__builtin_amdgcn_readlane(__float_as_uint(v), (unsigned)i));
}

__device__ __forceinline__ float wave_max(float v) {
#pragma unroll
  for (int off = 32; off; off >>= 1) v = fmaxf(v, __shfl_xor(v, off, 64));
  return v;
}
__device__ __forceinline__ float wave_sum(float v) {
#pragma unroll
  for (int off = 32; off; off >>= 1) v += __shfl_xor(v, off, 64);
  return v;
}
__device__ __forceinline__ int wave_sum_i(int v) {
#pragma unroll
  for (int off = 32; off; off >>= 1) v += __shfl_xor(v, off, 64);
  return v;
}

// ---- prep: derive per-batch lengths from the prefix mask; zero accumulator.
// mask dtype is detected from content: lengths >= 512 guarantee the first 4
// elements are all true.  u8 layout -> first dword 0x01010101; int32 -> 1,1;
// int64 -> 1,0.
__global__ __launch_bounds__(64) void crf_prep(const unsigned int* __restrict__ m32,
                                               int* __restrict__ lens,
                                               float* __restrict__ acc) {
  const int b = blockIdx.x;
  const int lane = threadIdx.x;
  int s = 0;
  const unsigned v0 = m32[0];
  if (v0 == 0x01010101u) {                    // bool as bytes
    const uint4* mv = (const uint4*)m32;      // row = 1024 B = 64 uint4
    uint4 x = mv[b * 64 + lane];
    s  = (int)(((x.x & 0x01010101u) * 0x01010101u) >> 24);
    s += (int)(((x.y & 0x01010101u) * 0x01010101u) >> 24);
    s += (int)(((x.z & 0x01010101u) * 0x01010101u) >> 24);
    s += (int)(((x.w & 0x01010101u) * 0x01010101u) >> 24);
  } else if (m32[1] == 0u) {                  // int64
#pragma unroll
    for (int k = 0; k < 16; ++k)
      s += (int)m32[((size_t)b * LL + k * 64 + lane) * 2];
  } else {                                    // int32
    const int* mi = (const int*)m32;
#pragma unroll
    for (int k = 0; k < 16; ++k)
      s += mi[b * LL + k * 64 + lane];
  }
  s = wave_sum_i(s);
  if (lane == 0) {
    lens[b] = s;
    if (b == 0) *acc = 0.f;
  }
}

// ---- main: one wave per batch, lane j = tag state j.
// Forward recursion kept in exp space with per-step bias e^-6 and renorm
// every 8 steps:  p[j] <- exp(ft[j]-6) * sum_i p[i]*E[i][j].
__global__ __launch_bounds__(64) void crf_main(const float* __restrict__ feats,
                                               const float* __restrict__ trans,
                                               const int* __restrict__ tags,
                                               const int* __restrict__ lens,
                                               float* __restrict__ acc) {
  const int b = blockIdx.x;
  const int lane = threadIdx.x;
  const bool jok = lane < TT;
  const int j = jok ? lane : TT - 1;          // clamp keeps loads in-bounds
  const int len = lens[b];                    // uniform

  // E column j in registers; zero for inactive lanes so their p stays 0.
  float e[TT];
#pragma unroll
  for (int i = 0; i < TT; ++i) {
    const float tv = trans[i * TT + j];
    e[i] = jok ? __expf(tv) : 0.f;
  }
  const float tl = jok ? __expf(trans[j * TT + STOP_TAG]) : 0.f;

  const float* fp = feats + (size_t)b * LL * TT + j;
  // part0 = f[0] + trans[START]  ->  p0 = exp(f0)*E[START][j]
  float p = __expf(fp[0]) * e[START_TAG];
  float carry = 0.f;

  // 4-deep feats prefetch (len >= 512 so t=1..4 always valid)
  float f1 = fp[1 * TT];
  float f2 = fp[2 * TT];
  float f3 = fp[3 * TT];
  float f4 = fp[4 * TT];

#pragma unroll 8
  for (int t = 1; t < len; ++t) {
    const float eft = __expf(f1 - 6.0f);      // biased emission factor
    f1 = f2; f2 = f3; f3 = f4;
    const int tp = t + 4;
    f4 = (tp < len) ? fp[(size_t)tp * TT] : 0.f;

    float a0 = 0.f, a1 = 0.f, a2 = 0.f, a3 = 0.f;
#pragma unroll
    for (int i = 0; i < TT; i += 4) {
      a0 = fmaf(rl(p, i + 0), e[i + 0], a0);
      a1 = fmaf(rl(p, i + 1), e[i + 1], a1);
      a2 = fmaf(rl(p, i + 2), e[i + 2], a2);
      a3 = fmaf(rl(p, i + 3), e[i + 3], a3);
    }
    p = ((a0 + a1) + (a2 + a3)) * eft;

    if ((t & 7) == 0) {                       // renormalize every 8 steps
      const float m = wave_max(p);
      carry += __logf(m);
      p *= (1.0f / m);
    }
  }

  // forward score: log(sum_i p[i]*exp(trans[i][STOP])) + carry + bias payback
  const float s = wave_sum(p * tl);
  const float fwd = __logf(s) + carry + 6.0f * (float)(len - 1);

  // gold score: lane-parallel over time
  const int* tgb = tags + b * LL;
  float g = 0.f;
  for (int base = 0; base < len; base += 64) {
    const int t = base + lane;
    if (t < len) {
      const int tag = tgb[t];
      const int prev = (t == 0) ? START_TAG : tgb[t - 1];
      g += feats[((size_t)b * LL + t) * TT + tag] + trans[prev * TT + tag];
    }
  }
  g = wave_sum(g);

  if (lane == 0) {
    const int last = tgb[len - 1];
    g += trans[last * TT + STOP_TAG];
    atomicAdd(acc, fwd - g);
  }
}

__global__ void crf_fin(const float* __restrict__ acc, float* __restrict__ out) {
  out[0] = acc[0] * (1.0f / (float)BB);
}

extern "C" void kernel_launch(void* const* d_in, const int* in_sizes, int n_in,
                              void* d_out, int out_size, void* d_ws, size_t ws_size,
                              hipStream_t stream) {
  const float* feats        = (const float*)d_in[0];
  const float* trans        = (const float*)d_in[1];
  const unsigned int* mask  = (const unsigned int*)d_in[2];
  const int* tags           = (const int*)d_in[3];

  float* acc = (float*)d_ws;                       // 1 float accumulator
  int* lens  = (int*)((char*)d_ws + 64);           // 512 ints

  crf_prep<<<BB, 64, 0, stream>>>(mask, lens, acc);
  crf_main<<<BB, 64, 0, stream>>>(feats, trans, tags, lens, acc);
  crf_fin<<<1, 1, 0, stream>>>(acc, (float*)d_out);
}

// Round 2
// 384.669 us; speedup vs baseline: 1.7635x; 1.7635x over previous
//
#include <hip/hip_runtime.h>

#define BB 512
#define LL 1024
#define TT 52
#define START_TAG 50   // T-2
#define STOP_TAG  51   // T-1

__device__ __forceinline__ float rl(float v, int i) {
  return __uint_as_float(__builtin_amdgcn_readlane(__float_as_uint(v), (unsigned)i));
}
__device__ __forceinline__ float wave_max(float v) {
#pragma unroll
  for (int off = 32; off; off >>= 1) v = fmaxf(v, __shfl_xor(v, off, 64));
  return v;
}
__device__ __forceinline__ float wave_sum(float v) {
#pragma unroll
  for (int off = 32; off; off >>= 1) v += __shfl_xor(v, off, 64);
  return v;
}
__device__ __forceinline__ int wave_sum_i(int v) {
#pragma unroll
  for (int off = 32; off; off >>= 1) v += __shfl_xor(v, off, 64);
  return v;
}

// One wave per batch; lane j = tag state j.  Forward recursion in exp space
// with per-step bias e^-6 and renorm every 8 steps.
__global__ __launch_bounds__(64, 1) void crf_main(
    const float* __restrict__ feats, const float* __restrict__ trans,
    const void* __restrict__ maskp, const int* __restrict__ tags,
    float* __restrict__ res) {
  const int b = blockIdx.x;
  const int lane = threadIdx.x;
  const bool jok = lane < TT;
  const int j = jok ? lane : TT - 1;        // clamp keeps loads in-bounds

  // ---- per-block length from prefix mask (dtype sniffed from content:
  // len>=512 guarantees first elements true; u8->0x01010101, i32->1,1, i64->1,0)
  const unsigned* m32 = (const unsigned*)maskp;
  int s = 0;
  const unsigned v0 = m32[0];
  if (v0 == 0x01010101u) {                  // bool as bytes
    const uint4* mv = (const uint4*)maskp;  // row = 1024 B = 64 uint4
    uint4 x = mv[b * 64 + lane];
    s  = (int)(((x.x & 0x01010101u) * 0x01010101u) >> 24);
    s += (int)(((x.y & 0x01010101u) * 0x01010101u) >> 24);
    s += (int)(((x.z & 0x01010101u) * 0x01010101u) >> 24);
    s += (int)(((x.w & 0x01010101u) * 0x01010101u) >> 24);
  } else if (m32[1] == 0u) {                // int64
    const unsigned long long* m64 = (const unsigned long long*)maskp;
#pragma unroll
    for (int k = 0; k < 16; ++k) s += (int)m64[(size_t)b * LL + k * 64 + lane];
  } else {                                  // int32
    const int* mi = (const int*)maskp;
#pragma unroll
    for (int k = 0; k < 16; ++k) s += mi[b * LL + k * 64 + lane];
  }
  const int len = wave_sum_i(s);            // uniform

  // ---- E column j, FORCED into VGPRs (opaque def prevents remat into loop)
  float e[TT];
#pragma unroll
  for (int i = 0; i < TT; ++i) {
    float ev = jok ? __expf(trans[i * TT + j]) : 0.f;
    asm volatile("" : "+v"(ev));
    e[i] = ev;
  }
  const float tl = jok ? __expf(trans[j * TT + STOP_TAG]) : 0.f;

  const float* fp = feats + (size_t)b * LL * TT + j;
  float p = __expf(fp[0]) * e[START_TAG];   // part0 = f0 + trans[START]
  float carry2 = 0.f;                       // log2 of accumulated renorms

#define CRF_STEP(FV)                                              \
  {                                                               \
    const float eft = __expf((FV)-6.0f);                          \
    float a0 = 0.f, a1 = 0.f, a2 = 0.f, a3 = 0.f;                 \
    _Pragma("unroll") for (int i = 0; i < TT; i += 4) {           \
      a0 = fmaf(rl(p, i + 0), e[i + 0], a0);                      \
      a1 = fmaf(rl(p, i + 1), e[i + 1], a1);                      \
      a2 = fmaf(rl(p, i + 2), e[i + 2], a2);                      \
      a3 = fmaf(rl(p, i + 3), e[i + 3], a3);                      \
    }                                                             \
    p = ((a0 + a1) + (a2 + a3)) * eft;                            \
  }

  const int nsteps = len - 1;               // steps t = 1 .. len-1
  const int nchunk = nsteps >> 3;
  const int ntail = nsteps & 7;

  float fb[8];                              // emissions for current 8 steps
#pragma unroll
  for (int k = 0; k < 8; ++k) fb[k] = fp[(size_t)(1 + k) * TT];  // len>=512

  int tbase = 1;
  for (int c = 0; c < nchunk; ++c) {
    float fn[8];                            // prefetch next chunk (~8 steps ahead)
#pragma unroll
    for (int k = 0; k < 8; ++k) {
      int tt = tbase + 8 + k;
      tt = tt < len ? tt : len - 1;         // clamp: harmless in-bounds load
      fn[k] = fp[(size_t)tt * TT];
    }
#pragma unroll
    for (int k = 0; k < 8; ++k) CRF_STEP(fb[k]);
    const float m = wave_max(p);            // renorm every 8 steps
    carry2 += __log2f(m);
    p *= __builtin_amdgcn_rcpf(m);
#pragma unroll
    for (int k = 0; k < 8; ++k) fb[k] = fn[k];
    tbase += 8;
  }
#pragma unroll
  for (int k = 0; k < 8; ++k)               // tail, statically indexed
    if (k < ntail) CRF_STEP(fb[k]);

  // forward score = log(sum p_i * e^trans[i,STOP]) + renorms + bias payback
  const float sfin = wave_sum(p * tl);
  const float fwd =
      (__log2f(sfin) + carry2) * 0.6931471805599453f + 6.0f * (float)(len - 1);

  // ---- gold score, lane-parallel over time
  const int* tgb = tags + b * LL;
  float g = 0.f;
  for (int base = 0; base < len; base += 64) {
    const int t = base + lane;
    if (t < len) {
      const int tag = tgb[t];
      const int prev = (t == 0) ? START_TAG : tgb[t - 1];
      g += feats[((size_t)b * LL + t) * TT + tag] + trans[prev * TT + tag];
    }
  }
  g = wave_sum(g);

  if (lane == 0) {
    g += trans[tgb[len - 1] * TT + STOP_TAG];
    res[b] = fwd - g;
  }
#undef CRF_STEP
}

__global__ __launch_bounds__(64) void crf_fin(const float* __restrict__ res,
                                              float* __restrict__ out) {
  float s = 0.f;
#pragma unroll
  for (int k = 0; k < 8; ++k) s += res[threadIdx.x + k * 64];
  s = wave_sum(s);
  if (threadIdx.x == 0) out[0] = s * (1.0f / (float)BB);
}

extern "C" void kernel_launch(void* const* d_in, const int* in_sizes, int n_in,
                              void* d_out, int out_size, void* d_ws, size_t ws_size,
                              hipStream_t stream) {
  const float* feats = (const float*)d_in[0];
  const float* trans = (const float*)d_in[1];
  const void* mask   = (const void*)d_in[2];
  const int* tags    = (const int*)d_in[3];

  float* res = (float*)d_ws;                // 512 per-batch results

  crf_main<<<BB, 64, 0, stream>>>(feats, trans, mask, tags, res);
  crf_fin<<<1, 64, 0, stream>>>(res, (float*)d_out);
}